// Round 2
// baseline (408.533 us; speedup 1.0000x reference)
//
#include <hip/hip_runtime.h>
#include <hip/hip_bf16.h>
#include <hip/hip_cooperative_groups.h>
#include <math.h>

namespace cg = cooperative_groups;

// Shapes fixed by setup_inputs(): B=64, C=128, H=56, W=56.
// C from in_sizes[1] (gamma); HW hard-coded (in_sizes can't split B vs H*W).
constexpr int HW  = 56 * 56;   // 3136
constexpr int HW4 = HW / 4;    // 784 float4 per plane

// Round-to-nearest-even fp32 -> bf16 -> fp32, matching jnp astype(bfloat16).
__device__ __forceinline__ float qbf(float f) {
    unsigned u = __float_as_uint(f);
    u += 0x7fffu + ((u >> 16) & 1u);
    u &= 0xffff0000u;
    return __uint_as_float(u);
}

// Workspace layout (floats)
constexpr int WS_MAX = 0;          // [4096]
constexpr int WS_MIN = 4096;       // [4096]
constexpr int WS_SUM = 8192;       // [4096]
constexpr int WS_AVG = 12288;      // [1024]
constexpr int WS_SCL = 13312;      // [1024]

__global__ __launch_bounds__(256, 4) void fused_kernel(
    const float* __restrict__ x, const float* __restrict__ gamma,
    const float* __restrict__ beta, const int* __restrict__ nch_p,
    int C, int n, unsigned total, float* __restrict__ ws, float* __restrict__ out)
{
    const int nch = *nch_p;
    const int cs  = n / nch;        // chunk size (elements per (c,chunk))
    const int P   = C * nch;

    float* ws_max = ws + WS_MAX;
    float* ws_min = ws + WS_MIN;
    float* ws_sum = ws + WS_SUM;
    float* avgv   = ws + WS_AVG;
    float* sclv   = ws + WS_SCL;

    __shared__ float smax[4], smin[4], ssum[4];

    const bool plane_mode = (cs % HW == 0) && ((total % (unsigned)HW) == 0u);

    // ---------------- phase 1: per-(channel, chunk) max / min / sum ----------------
    for (int p = blockIdx.x; p < P; p += gridDim.x) {
        const int c = p / nch;
        const int j = p - c * nch;

        float vmax = -INFINITY, vmin = INFINITY, vsum = 0.f;

        if (plane_mode) {
            // chunk j = full planes b0..b0+ppc-1 of channel c.
            // SAME per-thread element assignment as the (passing) R1 kernel:
            // thread t handles flat float4 indices t, t+256, ... within the chunk.
            const int ppc  = cs / HW;       // planes per chunk
            const int b0   = j * ppc;
            const int tot4 = ppc * HW4;
            for (int t = threadIdx.x; t < tot4; t += blockDim.x) {
                const int b = t / HW4;      // constexpr divisor -> magic mul
                const int r = t - b * HW4;
                const float4 v = *reinterpret_cast<const float4*>(
                    x + ((size_t)(b0 + b) * C + c) * HW + 4 * r);
                const float a0 = qbf(v.x), a1 = qbf(v.y), a2 = qbf(v.z), a3 = qbf(v.w);
                vmax = fmaxf(vmax, fmaxf(fmaxf(a0, a1), fmaxf(a2, a3)));
                vmin = fminf(vmin, fminf(fminf(a0, a1), fminf(a2, a3)));
                vsum += (a0 + a1) + (a2 + a3);
            }
        } else {
            for (int t = threadIdx.x; t < cs; t += blockDim.x) {
                const int f = j * cs + t;
                const int b = f / HW;
                const int r = f - b * HW;
                const float a = qbf(x[((size_t)b * C + c) * HW + r]);
                vmax = fmaxf(vmax, a);
                vmin = fminf(vmin, a);
                vsum += a;
            }
        }

        #pragma unroll
        for (int off = 32; off > 0; off >>= 1) {
            vmax = fmaxf(vmax, __shfl_xor(vmax, off));
            vmin = fminf(vmin, __shfl_xor(vmin, off));
            vsum += __shfl_xor(vsum, off);
        }
        const int wave = threadIdx.x >> 6;
        if ((threadIdx.x & 63) == 0) { smax[wave] = vmax; smin[wave] = vmin; ssum[wave] = vsum; }
        __syncthreads();
        if (threadIdx.x == 0) {
            float m = smax[0], mi = smin[0], s = ssum[0];
            for (int w = 1; w < 4; ++w) {
                m = fmaxf(m, smax[w]); mi = fminf(mi, smin[w]); s += ssum[w];
            }
            ws_max[p] = m; ws_min[p] = mi; ws_sum[p] = s;
        }
        __syncthreads();
    }

    cg::this_grid().sync();

    // ---------------- phase 2: per-channel avg & scale (block 0 only) ----------------
    if (blockIdx.x == 0) {
        for (int c = threadIdx.x; c < C; c += blockDim.x) {
            float smx = 0.f, smn = 0.f, stot = 0.f;
            for (int j = 0; j < nch; ++j) {        // same sequential order as R1 (absmax 0.0)
                smx  += ws_max[c * nch + j];
                smn  += ws_min[c * nch + j];
                stot += ws_sum[c * nch + j];
            }
            smx = qbf(smx);
            smn = qbf(smn);
            const float avg_max = qbf(smx / (float)nch);
            const float avg_min = qbf(smn / (float)nch);
            const float tq      = qbf(stot);
            const float avg     = qbf(tq / (float)n);
            const double sf_d   = 1.0 / sqrt(2.0 * log((double)cs));
            const float scale_fix = (float)sf_d;
            const float scale = qbf(1.0f / ((avg_max - avg_min) * scale_fix + 1e-5f));
            avgv[c] = avg;
            sclv[c] = scale;
        }
    }

    cg::this_grid().sync();

    // ---------------- phase 3: normalize ----------------
    if (plane_mode) {
        const int planes = (int)(total / (unsigned)HW);   // B*C
        for (int pl = blockIdx.x; pl < planes; pl += gridDim.x) {
            const int c = pl % C;                         // block-uniform -> scalar loads below
            const float a = avgv[c], s = sclv[c], g = qbf(gamma[c]), bt = beta[c];
            const float* xp = x   + (size_t)pl * HW;
            float*       op = out + (size_t)pl * HW;
            for (int t = threadIdx.x; t < HW4; t += blockDim.x) {
                const float4 v = *reinterpret_cast<const float4*>(xp + 4 * t);
                float4 o;
                o.x = qbf(qbf((qbf(v.x) - a) * s) * g + bt);
                o.y = qbf(qbf((qbf(v.y) - a) * s) * g + bt);
                o.z = qbf(qbf((qbf(v.z) - a) * s) * g + bt);
                o.w = qbf(qbf((qbf(v.w) - a) * s) * g + bt);
                *reinterpret_cast<float4*>(op + 4 * t) = o;
            }
        }
    } else {
        const unsigned stride = gridDim.x * blockDim.x;
        for (unsigned i = blockIdx.x * blockDim.x + threadIdx.x; i < total; i += stride) {
            const int c = (int)((i / (unsigned)HW) % (unsigned)C);
            const float a = avgv[c], s = sclv[c], g = qbf(gamma[c]), bt = beta[c];
            out[i] = qbf(qbf((qbf(x[i]) - a) * s) * g + bt);
        }
    }
}

extern "C" void kernel_launch(void* const* d_in, const int* in_sizes, int n_in,
                              void* d_out, int out_size, void* d_ws, size_t ws_size,
                              hipStream_t stream) {
    const float* x     = (const float*)d_in[0];
    const float* gamma = (const float*)d_in[1];
    const float* beta  = (const float*)d_in[2];
    const int*   nch_p = (const int*)d_in[3];
    float* outp = (float*)d_out;
    float* ws   = (float*)d_ws;

    const int      C     = in_sizes[1];            // 128
    const unsigned total = (unsigned)in_sizes[0];  // B*C*H*W
    const int      n     = (int)(total / (unsigned)C);

    void* args[] = { (void*)&x, (void*)&gamma, (void*)&beta, (void*)&nch_p,
                     (void*)&C, (void*)&n, (void*)&total, (void*)&ws, (void*)&outp };
    hipLaunchCooperativeKernel((void*)fused_kernel, dim3(1024), dim3(256),
                               args, 0, stream);
}

// Round 3
// 205.143 us; speedup vs baseline: 1.9915x; 1.9915x over previous
//
#include <hip/hip_runtime.h>
#include <hip/hip_bf16.h>
#include <math.h>

// Shapes fixed by setup_inputs(): B=64, C=128, H=56, W=56.
// C from in_sizes[1] (gamma); HW hard-coded (in_sizes can't split B vs H*W).
constexpr int HW  = 56 * 56;   // 3136
constexpr int HW4 = HW / 4;    // 784 float4 per plane

// Round-to-nearest-even fp32 -> bf16 -> fp32, matching jnp astype(bfloat16).
__device__ __forceinline__ float qbf(float f) {
    unsigned u = __float_as_uint(f);
    u += 0x7fffu + ((u >> 16) & 1u);
    u &= 0xffff0000u;
    return __uint_as_float(u);
}

// ---------------- Kernel A: per-(channel, chunk) max / min / sum ----------------
// One block per (c, chunk) pair. Chunk = ppc consecutive planes of channel c.
// ILP: unroll over the 8 planes -> 8 independent float4 loads in flight.
__global__ __launch_bounds__(256) void stats_kernel(
    const float* __restrict__ x, const int* __restrict__ nch_p,
    int C, int n,
    float* __restrict__ ws_max, float* __restrict__ ws_min, float* __restrict__ ws_sum)
{
    const int nch = *nch_p;
    const int cs  = n / nch;        // chunk size (elements)
    const int P   = C * nch;

    __shared__ float smax[4], smin[4], ssum[4];

    for (int p = blockIdx.x; p < P; p += gridDim.x) {
        const int c = p / nch;
        const int j = p - c * nch;

        float vmax = -INFINITY, vmin = INFINITY, vsum = 0.f;

        if (cs % HW == 0) {
            const int ppc = cs / HW;                  // planes per chunk (8)
            const float* base = x + ((size_t)(j * ppc) * C + c) * HW;
            const size_t pstride = (size_t)C * HW;    // plane-to-plane stride

            if (ppc == 8) {
                for (int t = threadIdx.x; t < HW4; t += 256) {
                    #pragma unroll
                    for (int b = 0; b < 8; ++b) {     // 8 independent loads in flight
                        const float4 v = *reinterpret_cast<const float4*>(
                            base + b * pstride + 4 * t);
                        const float a0 = qbf(v.x), a1 = qbf(v.y),
                                    a2 = qbf(v.z), a3 = qbf(v.w);
                        vmax = fmaxf(vmax, fmaxf(fmaxf(a0, a1), fmaxf(a2, a3)));
                        vmin = fminf(vmin, fminf(fminf(a0, a1), fminf(a2, a3)));
                        vsum += (a0 + a1) + (a2 + a3);
                    }
                }
            } else {
                for (int t = threadIdx.x; t < HW4; t += 256) {
                    for (int b = 0; b < ppc; ++b) {
                        const float4 v = *reinterpret_cast<const float4*>(
                            base + b * pstride + 4 * t);
                        const float a0 = qbf(v.x), a1 = qbf(v.y),
                                    a2 = qbf(v.z), a3 = qbf(v.w);
                        vmax = fmaxf(vmax, fmaxf(fmaxf(a0, a1), fmaxf(a2, a3)));
                        vmin = fminf(vmin, fminf(fminf(a0, a1), fminf(a2, a3)));
                        vsum += (a0 + a1) + (a2 + a3);
                    }
                }
            }
        } else {
            // generic fallback: scalar walk of the chunk
            for (int t = threadIdx.x; t < cs; t += 256) {
                const int f = j * cs + t;
                const int b = f / HW;
                const int r = f - b * HW;
                const float a = qbf(x[((size_t)b * C + c) * HW + r]);
                vmax = fmaxf(vmax, a);
                vmin = fminf(vmin, a);
                vsum += a;
            }
        }

        #pragma unroll
        for (int off = 32; off > 0; off >>= 1) {
            vmax = fmaxf(vmax, __shfl_xor(vmax, off));
            vmin = fminf(vmin, __shfl_xor(vmin, off));
            vsum += __shfl_xor(vsum, off);
        }
        const int wave = threadIdx.x >> 6;
        if ((threadIdx.x & 63) == 0) { smax[wave] = vmax; smin[wave] = vmin; ssum[wave] = vsum; }
        __syncthreads();
        if (threadIdx.x == 0) {
            float m = smax[0], mi = smin[0], s = ssum[0];
            for (int w = 1; w < 4; ++w) {
                m = fmaxf(m, smax[w]); mi = fminf(mi, smin[w]); s += ssum[w];
            }
            ws_max[p] = m; ws_min[p] = mi; ws_sum[p] = s;
        }
        __syncthreads();
    }
}

// ---------------- Kernel B: per-channel avg & scale ----------------
__global__ __launch_bounds__(256) void finalize_kernel(
    const float* __restrict__ ws_max, const float* __restrict__ ws_min,
    const float* __restrict__ ws_sum, const int* __restrict__ nch_p,
    int C, int n, float* __restrict__ avg_out, float* __restrict__ scale_out)
{
    const int c = blockIdx.x * blockDim.x + threadIdx.x;
    if (c >= C) return;
    const int nch = *nch_p;

    float smax = 0.f, smin = 0.f, stot = 0.f;
    for (int j = 0; j < nch; ++j) {
        smax += ws_max[c * nch + j];
        smin += ws_min[c * nch + j];
        stot += ws_sum[c * nch + j];
    }
    smax = qbf(smax);
    smin = qbf(smin);
    const float avg_max = qbf(smax / (float)nch);
    const float avg_min = qbf(smin / (float)nch);
    const float total   = qbf(stot);
    const float avg     = qbf(total / (float)n);

    const int cs = n / nch;
    const double sf_d = 1.0 / sqrt(2.0 * log((double)cs));
    const float scale_fix = (float)sf_d;
    const float scale = qbf(1.0f / ((avg_max - avg_min) * scale_fix + 1e-5f));

    avg_out[c]   = avg;
    scale_out[c] = scale;
}

// ---------------- Kernel C: normalize, one block per (b,c) plane ----------------
__global__ __launch_bounds__(256) void norm_plane_kernel(
    const float* __restrict__ x, const float* __restrict__ gamma,
    const float* __restrict__ beta, const float* __restrict__ avg,
    const float* __restrict__ scale, int C, float* __restrict__ out)
{
    const int pl = blockIdx.x;
    const int c  = pl % C;                      // wave-uniform -> scalar broadcasts
    const float a = avg[c], s = scale[c], g = qbf(gamma[c]), bt = beta[c];
    const float* xp = x   + (size_t)pl * HW;
    float*       op = out + (size_t)pl * HW;
    for (int t = threadIdx.x; t < HW4; t += 256) {
        const float4 v = *reinterpret_cast<const float4*>(xp + 4 * t);
        float4 o;
        o.x = qbf(qbf((qbf(v.x) - a) * s) * g + bt);
        o.y = qbf(qbf((qbf(v.y) - a) * s) * g + bt);
        o.z = qbf(qbf((qbf(v.z) - a) * s) * g + bt);
        o.w = qbf(qbf((qbf(v.w) - a) * s) * g + bt);
        *reinterpret_cast<float4*>(op + 4 * t) = o;
    }
}

// generic fallback if total % HW != 0 (not expected with the fixed shapes)
__global__ __launch_bounds__(256) void norm_generic_kernel(
    const float* __restrict__ x, const float* __restrict__ gamma,
    const float* __restrict__ beta, const float* __restrict__ avg,
    const float* __restrict__ scale, int C, unsigned total, float* __restrict__ out)
{
    const unsigned stride = gridDim.x * blockDim.x;
    for (unsigned i = blockIdx.x * blockDim.x + threadIdx.x; i < total; i += stride) {
        const int c = (int)((i / (unsigned)HW) % (unsigned)C);
        const float a = avg[c], s = scale[c], g = qbf(gamma[c]), bt = beta[c];
        out[i] = qbf(qbf((qbf(x[i]) - a) * s) * g + bt);
    }
}

extern "C" void kernel_launch(void* const* d_in, const int* in_sizes, int n_in,
                              void* d_out, int out_size, void* d_ws, size_t ws_size,
                              hipStream_t stream) {
    const float* x     = (const float*)d_in[0];
    const float* gamma = (const float*)d_in[1];
    const float* beta  = (const float*)d_in[2];
    const int*   nch_p = (const int*)d_in[3];
    float* out = (float*)d_out;

    const int      C     = in_sizes[1];            // 128
    const unsigned total = (unsigned)in_sizes[0];  // B*C*H*W
    const int      n     = (int)(total / (unsigned)C);

    constexpr int Pmax = 4096, Cmax = 1024;
    float* ws_f   = (float*)d_ws;
    float* ws_max = ws_f;
    float* ws_min = ws_f + Pmax;
    float* ws_sum = ws_f + 2 * Pmax;
    float* avg    = ws_f + 3 * Pmax;
    float* scale  = ws_f + 3 * Pmax + Cmax;

    stats_kernel<<<1024, 256, 0, stream>>>(x, nch_p, C, n, ws_max, ws_min, ws_sum);
    finalize_kernel<<<(C + 255) / 256, 256, 0, stream>>>(ws_max, ws_min, ws_sum,
                                                         nch_p, C, n, avg, scale);
    if (total % (unsigned)HW == 0u) {
        const int planes = (int)(total / (unsigned)HW);   // B*C = 8192
        norm_plane_kernel<<<planes, 256, 0, stream>>>(x, gamma, beta, avg, scale, C, out);
    } else {
        norm_generic_kernel<<<2048, 256, 0, stream>>>(x, gamma, beta, avg, scale, C, total, out);
    }
}

// Round 6
// 200.923 us; speedup vs baseline: 2.0333x; 1.0210x over previous
//
#include <hip/hip_runtime.h>
#include <hip/hip_bf16.h>
#include <math.h>

// Shapes fixed by setup_inputs(): B=64, C=128, H=56, W=56.
// C from in_sizes[1] (gamma); HW hard-coded (in_sizes can't split B vs H*W).
constexpr int HW  = 56 * 56;   // 3136
constexpr int HW4 = HW / 4;    // 784 float4 per plane

typedef float vfloat4 __attribute__((ext_vector_type(4)));  // native vec for nt-store

// Round-to-nearest-even fp32 -> bf16 -> fp32, matching jnp astype(bfloat16).
__device__ __forceinline__ float qbf(float f) {
    unsigned u = __float_as_uint(f);
    u += 0x7fffu + ((u >> 16) & 1u);
    u &= 0xffff0000u;
    return __uint_as_float(u);
}

// ---------------- Kernel A: per-(channel, chunk) max / min / sum ----------------
// One block per (c, chunk) pair. Chunk = ppc consecutive planes of channel c.
__global__ __launch_bounds__(256) void stats_kernel(
    const float* __restrict__ x, const int* __restrict__ nch_p,
    int C, int n,
    float* __restrict__ ws_max, float* __restrict__ ws_min, float* __restrict__ ws_sum)
{
    const int nch = *nch_p;
    const int cs  = n / nch;        // chunk size (elements)
    const int P   = C * nch;

    __shared__ float smax[4], smin[4], ssum[4];

    for (int p = blockIdx.x; p < P; p += gridDim.x) {
        const int c = p / nch;
        const int j = p - c * nch;

        float vmax = -INFINITY, vmin = INFINITY, vsum = 0.f;

        if (cs % HW == 0) {
            const int ppc = cs / HW;                  // planes per chunk (8)
            const float* base = x + ((size_t)(j * ppc) * C + c) * HW;
            const size_t pstride = (size_t)C * HW;    // plane-to-plane stride

            if (ppc == 8) {
                for (int t = threadIdx.x; t < HW4; t += 256) {
                    #pragma unroll
                    for (int b = 0; b < 8; ++b) {
                        const float4 v = *reinterpret_cast<const float4*>(
                            base + b * pstride + 4 * t);
                        const float a0 = qbf(v.x), a1 = qbf(v.y),
                                    a2 = qbf(v.z), a3 = qbf(v.w);
                        vmax = fmaxf(vmax, fmaxf(fmaxf(a0, a1), fmaxf(a2, a3)));
                        vmin = fminf(vmin, fminf(fminf(a0, a1), fminf(a2, a3)));
                        vsum += (a0 + a1) + (a2 + a3);
                    }
                }
            } else {
                for (int t = threadIdx.x; t < HW4; t += 256) {
                    for (int b = 0; b < ppc; ++b) {
                        const float4 v = *reinterpret_cast<const float4*>(
                            base + b * pstride + 4 * t);
                        const float a0 = qbf(v.x), a1 = qbf(v.y),
                                    a2 = qbf(v.z), a3 = qbf(v.w);
                        vmax = fmaxf(vmax, fmaxf(fmaxf(a0, a1), fmaxf(a2, a3)));
                        vmin = fminf(vmin, fminf(fminf(a0, a1), fminf(a2, a3)));
                        vsum += (a0 + a1) + (a2 + a3);
                    }
                }
            }
        } else {
            for (int t = threadIdx.x; t < cs; t += 256) {
                const int f = j * cs + t;
                const int b = f / HW;
                const int r = f - b * HW;
                const float a = qbf(x[((size_t)b * C + c) * HW + r]);
                vmax = fmaxf(vmax, a);
                vmin = fminf(vmin, a);
                vsum += a;
            }
        }

        #pragma unroll
        for (int off = 32; off > 0; off >>= 1) {
            vmax = fmaxf(vmax, __shfl_xor(vmax, off));
            vmin = fminf(vmin, __shfl_xor(vmin, off));
            vsum += __shfl_xor(vsum, off);
        }
        const int wave = threadIdx.x >> 6;
        if ((threadIdx.x & 63) == 0) { smax[wave] = vmax; smin[wave] = vmin; ssum[wave] = vsum; }
        __syncthreads();
        if (threadIdx.x == 0) {
            float m = smax[0], mi = smin[0], s = ssum[0];
            for (int w = 1; w < 4; ++w) {
                m = fmaxf(m, smax[w]); mi = fminf(mi, smin[w]); s += ssum[w];
            }
            ws_max[p] = m; ws_min[p] = mi; ws_sum[p] = s;
        }
        __syncthreads();
    }
}

// helper: per-channel avg & scale from chunk partials (reference quantization chain)
__device__ __forceinline__ void channel_stats(
    const float* __restrict__ ws_max, const float* __restrict__ ws_min,
    const float* __restrict__ ws_sum, int c, int nch, int n,
    float& avg_out, float& scale_out)
{
    float smx = 0.f, smn = 0.f, stot = 0.f;
    for (int j = 0; j < nch; ++j) {          // same sequential order as R1/R3 (absmax 0.0)
        smx  += ws_max[c * nch + j];
        smn  += ws_min[c * nch + j];
        stot += ws_sum[c * nch + j];
    }
    smx = qbf(smx);
    smn = qbf(smn);
    const float avg_max = qbf(smx / (float)nch);
    const float avg_min = qbf(smn / (float)nch);
    const float tq      = qbf(stot);
    avg_out = qbf(tq / (float)n);
    const int cs = n / nch;
    const double sf_d = 1.0 / sqrt(2.0 * log((double)cs));
    const float scale_fix = (float)sf_d;
    scale_out = qbf(1.0f / ((avg_max - avg_min) * scale_fix + 1e-5f));
}

// ---------------- Kernel B: normalize, finalize folded in. grid = (C, B) ----------------
__global__ __launch_bounds__(256) void norm_plane_kernel(
    const float* __restrict__ x, const float* __restrict__ gamma,
    const float* __restrict__ beta,
    const float* __restrict__ ws_max, const float* __restrict__ ws_min,
    const float* __restrict__ ws_sum, const int* __restrict__ nch_p,
    int C, int n, float* __restrict__ out)
{
    const int c = blockIdx.x;
    const int b = blockIdx.y;

    __shared__ float s_avg, s_scl;
    if (threadIdx.x == 0) {
        float a, s;
        channel_stats(ws_max, ws_min, ws_sum, c, *nch_p, n, a, s);
        s_avg = a; s_scl = s;
    }
    __syncthreads();

    const float a  = s_avg, s = s_scl;
    const float g  = qbf(gamma[c]);
    const float bt = beta[c];
    const float* xp = x   + ((size_t)b * C + c) * HW;
    float*       op = out + ((size_t)b * C + c) * HW;

    for (int t = threadIdx.x; t < HW4; t += 256) {
        const float4 v = *reinterpret_cast<const float4*>(xp + 4 * t);
        vfloat4 o;
        o.x = qbf(qbf((qbf(v.x) - a) * s) * g + bt);
        o.y = qbf(qbf((qbf(v.y) - a) * s) * g + bt);
        o.z = qbf(qbf((qbf(v.z) - a) * s) * g + bt);
        o.w = qbf(qbf((qbf(v.w) - a) * s) * g + bt);
        __builtin_nontemporal_store(o, reinterpret_cast<vfloat4*>(op + 4 * t));
    }
}

// ---------------- generic fallbacks (not used for the fixed shapes) ----------------
__global__ __launch_bounds__(256) void finalize_kernel(
    const float* __restrict__ ws_max, const float* __restrict__ ws_min,
    const float* __restrict__ ws_sum, const int* __restrict__ nch_p,
    int C, int n, float* __restrict__ avg_out, float* __restrict__ scale_out)
{
    const int c = blockIdx.x * blockDim.x + threadIdx.x;
    if (c >= C) return;
    float a, s;
    channel_stats(ws_max, ws_min, ws_sum, c, *nch_p, n, a, s);
    avg_out[c] = a; scale_out[c] = s;
}

__global__ __launch_bounds__(256) void norm_generic_kernel(
    const float* __restrict__ x, const float* __restrict__ gamma,
    const float* __restrict__ beta, const float* __restrict__ avg,
    const float* __restrict__ scale, int C, unsigned total, float* __restrict__ out)
{
    const unsigned stride = gridDim.x * blockDim.x;
    for (unsigned i = blockIdx.x * blockDim.x + threadIdx.x; i < total; i += stride) {
        const int c = (int)((i / (unsigned)HW) % (unsigned)C);
        const float a = avg[c], s = scale[c], g = qbf(gamma[c]), bt = beta[c];
        out[i] = qbf(qbf((qbf(x[i]) - a) * s) * g + bt);
    }
}

extern "C" void kernel_launch(void* const* d_in, const int* in_sizes, int n_in,
                              void* d_out, int out_size, void* d_ws, size_t ws_size,
                              hipStream_t stream) {
    const float* x     = (const float*)d_in[0];
    const float* gamma = (const float*)d_in[1];
    const float* beta  = (const float*)d_in[2];
    const int*   nch_p = (const int*)d_in[3];
    float* out = (float*)d_out;

    const int      C     = in_sizes[1];            // 128
    const unsigned total = (unsigned)in_sizes[0];  // B*C*H*W
    const int      n     = (int)(total / (unsigned)C);

    constexpr int Pmax = 4096, Cmax = 1024;
    float* ws_f   = (float*)d_ws;
    float* ws_max = ws_f;
    float* ws_min = ws_f + Pmax;
    float* ws_sum = ws_f + 2 * Pmax;
    float* avg    = ws_f + 3 * Pmax;
    float* scale  = ws_f + 3 * Pmax + Cmax;

    stats_kernel<<<1024, 256, 0, stream>>>(x, nch_p, C, n, ws_max, ws_min, ws_sum);

    if (total % (unsigned)HW == 0u && (total / (unsigned)HW) % (unsigned)C == 0u) {
        const int planes = (int)(total / (unsigned)HW);   // B*C = 8192
        const int B      = planes / C;                    // 64
        norm_plane_kernel<<<dim3(C, B), 256, 0, stream>>>(
            x, gamma, beta, ws_max, ws_min, ws_sum, nch_p, C, n, out);
    } else {
        finalize_kernel<<<(C + 255) / 256, 256, 0, stream>>>(ws_max, ws_min, ws_sum,
                                                             nch_p, C, n, avg, scale);
        norm_generic_kernel<<<2048, 256, 0, stream>>>(x, gamma, beta, avg, scale,
                                                      C, total, out);
    }
}